// Round 12
// baseline (4908.291 us; speedup 1.0000x reference)
//
#include <hip/hip_runtime.h>
#include <stdint.h>

// ---------------- problem constants ----------------
#define BATCH  128
#define TENC   256
#define TDEC   128
#define NSTEPS 384      // 256 encoder + 128 decoder timesteps
#define GP     2176     // G tile pitch bytes (h0 cols + 128B x/y XOR window)
#define HP     2048     // H tile pitch bytes (h1 cols)
#define HOFF   69632    // G = 32*2176 bytes, H starts here
#define SMEMSZ 135168   // 69632 + 32*2048
#define EXP    65       // exchange pitch in f32 words

typedef __attribute__((ext_vector_type(8))) short s16x8;
typedef __attribute__((ext_vector_type(4))) float f32x4;

// ---------------- workspace layout (bytes) ----------------
#define OFF_XBF 0u         // x bf16 [128][256][8]       512 KB
#define OFF_YBF 524288u    // y bf16 [128][128]           32 KB
#define OFF_H0  557056u    // h0 [2 par][128][1024] bf16, u-swizzled  512 KB
#define OFF_H1  1081344u   // h1 same                                 512 KB
#define OFF_BAR 1736704u   // [4 btile] x 2KB: cnt1 sub[4]@+i*256B, cnt2 sub[4]@+1KB+i*256B
#define WS_END  1744896u
#define OFF_PMU 2097152u   // mu partials  [128 t][4 bt][64 ut][32 er] f32 = 4 MB
#define OFF_PSG 6291456u   // sig partials  4 MB

__device__ __forceinline__ unsigned short f2bf(float f) {   // f32 -> bf16 RNE
  unsigned u = __float_as_uint(f);
  u = u + 0x7fffu + ((u >> 16) & 1u);
  return (unsigned short)(u >> 16);
}
__device__ __forceinline__ float sigm(float x) { return 1.f / (1.f + __expf(-x)); }
__device__ __forceinline__ float tanh_f(float x) {
  float a = fabsf(x);
  float e = __expf(-2.f * a);
  float t = (1.f - e) / (1.f + e);
  return x < 0.f ? -t : t;
}

// async global->LDS 16B/lane, COHERENT (sc0|sc1 = CPol 17): bypass stale L1/L2
__device__ __forceinline__ void glds16c(const void* g, void* l) {
  __builtin_amdgcn_global_load_lds((const __attribute__((address_space(1))) void*)g,
                                   (__attribute__((address_space(3))) void*)l, 16, 0, 17);
}
__device__ __forceinline__ unsigned ldcoh(const unsigned* p) {
  unsigned v;
  asm volatile("global_load_dword %0, %1, off sc0 sc1\n\ts_waitcnt vmcnt(0)"
               : "=v"(v) : "v"(p) : "memory");
  return v;
}
__device__ __forceinline__ void stcoh(unsigned* p, unsigned v) {
  asm volatile("global_store_dword %0, %1, off sc0 sc1" :: "v"(p), "v"(v) : "memory");
}
// 4-line split-counter poll: lanes read line (lane&3); 256B/iter footprint; one wave
__device__ __forceinline__ void pollcnt4(const unsigned* base, unsigned target, int lane) {
  const unsigned* p = base + (lane & 3) * 64;
  for (;;) {
    unsigned v = ldcoh(p);
    if (__all((int)v >= (int)target)) break;
    __builtin_amdgcn_s_sleep(1);
  }
}

#define BARRIER() do { __builtin_amdgcn_s_barrier(); asm volatile("" ::: "memory"); } while (0)
#define WAIT_LGKM() asm volatile("s_waitcnt lgkmcnt(0)" ::: "memory")
#define WAIT_VM()   asm volatile("s_waitcnt vmcnt(0)" ::: "memory")

// -------- resident-weight loader (bf16 MFMA B-frags, K-split stride-4 over waves) --------
__device__ __forceinline__ void load_weights(
    s16x8 (&wfa)[9][4], s16x8 (&wfb)[16][4],
    int w, int u0, int l15, int khi,
    const float* W0h, const float* W0x, int xk,
    const float* W1x, const float* W1h) {
#pragma unroll
  for (int j = 0; j < 9; ++j) {
    int kst = w + 4 * j;
#pragma unroll
    for (int n = 0; n < 4; ++n) {
      int g = n * 1024 + u0 + l15;
      s16x8 v;
#pragma unroll
      for (int e = 0; e < 8; ++e) ((unsigned short*)&v)[e] = 0;
      if (kst < 32) {
        const float* p = W0h + (size_t)g * 1024 + kst * 32 + khi * 8;
#pragma unroll
        for (int e = 0; e < 8; ++e) ((unsigned short*)&v)[e] = f2bf(p[e]);
      } else if (kst == 32) {
        if (khi == 0) {
#pragma unroll
          for (int e = 0; e < 8; ++e)
            if (e < xk) ((unsigned short*)&v)[e] = f2bf(W0x[(size_t)g * xk + e]);
        }
      }
      wfa[j][n] = v;
    }
  }
#pragma unroll
  for (int j = 0; j < 16; ++j) {
    int kst = w + 4 * j;
#pragma unroll
    for (int n = 0; n < 4; ++n) {
      int g = n * 1024 + u0 + l15;
      const float* p = (kst < 32)
          ? (W1x + (size_t)g * 1024 + kst * 32 + khi * 8)
          : (W1h + (size_t)g * 1024 + (kst - 32) * 32 + khi * 8);
      s16x8 v;
#pragma unroll
      for (int e = 0; e < 8; ++e) ((unsigned short*)&v)[e] = f2bf(p[e]);
      wfb[j][n] = v;
    }
  }
}

// ---------------- input conversion ----------------
__global__ void cvt_inputs(const float* __restrict__ x, const float* __restrict__ y,
                           unsigned short* __restrict__ xbf, unsigned short* __restrict__ ybf) {
  int i = blockIdx.x * 256 + threadIdx.x;
  if (i < 262144) xbf[i] = f2bf(x[i]);
  if (i < 16384) {
    int b = i >> 7, t = i & 127;
    ybf[i] = f2bf(y[b * 129 + t]);
  }
}

// ---------------- main persistent kernel ----------------
__global__ void __launch_bounds__(256, 1) lstm_main(
    const float* __restrict__ eWx0, const float* __restrict__ eWh0,
    const float* __restrict__ eB0a, const float* __restrict__ eB0b,
    const float* __restrict__ eWx1, const float* __restrict__ eWh1,
    const float* __restrict__ eB1a, const float* __restrict__ eB1b,
    const float* __restrict__ dWx0, const float* __restrict__ dWh0,
    const float* __restrict__ dB0a, const float* __restrict__ dB0b,
    const float* __restrict__ dWx1, const float* __restrict__ dWh1,
    const float* __restrict__ dB1a, const float* __restrict__ dB1b,
    const float* __restrict__ Wmu, const float* __restrict__ Wsig,
    const unsigned short* __restrict__ xbf, const unsigned short* __restrict__ ybf,
    unsigned short* h0buf, unsigned short* h1buf,
    float* pmu, float* psg, unsigned* bars) {
  __shared__ char smem[SMEMSZ];

  const int tid = threadIdx.x;
  const int wg = blockIdx.x;
  const int w = tid >> 6;
  const int lane = tid & 63;
  const int l15 = lane & 15;
  const int khi = lane >> 4;
  const int btile = wg & 3;        // sync group
  const int utile = wg >> 2;       // 0..63 -> 16 hidden units
  const int u0 = utile << 4;
  const int r0 = btile << 5;       // 32 batch rows
  const int key = (l15 & 7) << 4;  // XOR bank swizzle

  unsigned* cnt1 = bars + btile * 512;       // 4 sub-lines at +i*64 dwords (256B apart)
  unsigned* cnt2 = cnt1 + 256;               // 4 sub-lines, 1KB away
  unsigned* my1 = cnt1 + (utile & 3) * 64;
  unsigned* my2 = cnt2 + (utile & 3) * 64;

  // elementwise partition: erow = tid>>3 (coalesced stores), uslot = tid&7
  const int erow = tid >> 3;
  const int uslot = tid & 7;

  s16x8 wfa[9][4];
  s16x8 wfb[16][4];
  load_weights(wfa, wfb, w, u0, l15, khi, eWh0, eWx0, 8, eWx1, eWh1);

  float b0s[2][4], b1s[2][4];
#pragma unroll
  for (int jj = 0; jj < 2; ++jj) {
    int u = u0 + uslot * 2 + jj;
#pragma unroll
    for (int n = 0; n < 4; ++n) {
      b0s[jj][n] = eB0a[n * 1024 + u] + eB0b[n * 1024 + u];
      b1s[jj][n] = eB1a[n * 1024 + u] + eB1b[n * 1024 + u];
    }
  }
  const float wm0 = Wmu[u0 + uslot * 2], wm1 = Wmu[u0 + uslot * 2 + 1];
  const float wg0 = Wsig[u0 + uslot * 2], wg1 = Wsig[u0 + uslot * 2 + 1];

  float c0a = 0.f, c0b = 0.f, c1a = 0.f, c1b = 0.f;

  // pre-loop: zero G + H tiles (h0(-1)=0, h1(-1)=0, windows 0)
  {
    s16x8 z;
#pragma unroll
    for (int e = 0; e < 8; ++e) ((unsigned short*)&z)[e] = 0;
    for (int o = tid * 16; o < SMEMSZ; o += 4096) *(s16x8*)(smem + o) = z;
  }
  __syncthreads();

  for (int s = 0; s < NSTEPS; ++s) {
    const int enc = (s < 256) ? 1 : 0;
    const int t = enc ? s : (s - 256);
    const int par = s & 1;

    // (P1) bar2(s-1) poll at STEP-TOP, then H-DMA issue — shadow = window + L0 GEMM
    //      + exchange (drained at P4-end). Poll absorbs only group skew here.
    if (w == 3) pollcnt4(cnt2, 16u * (unsigned)s, lane);
    BARRIER();          // release; prev step's exH reads (P11) are behind prev barrier
#pragma unroll
    for (int rr = 0; rr < 8; ++rr) {
      int row = w * 8 + rr;
      const char* src = (const char*)(h1buf + (((size_t)par * BATCH + r0 + row) << 10));
      char* dst = smem + HOFF + row * HP;
      glds16c(src + lane * 16, dst);
      glds16c(src + 1024 + lane * 16, dst + 1024);
    }
    // (P1b) x/y window write (w0-only writer AND reader: wave-local, no barrier)
    if (tid < 32) {
      char* wb = smem + tid * GP + 2048;
      s16x8 z;
#pragma unroll
      for (int e = 0; e < 8; ++e) ((unsigned short*)&z)[e] = 0;
#pragma unroll
      for (int q = 0; q < 8; ++q) *(s16x8*)(wb + q * 16) = z;   // clear exG residue
      int slot = (tid & 7) << 4;
      if (enc) {
        *(s16x8*)(wb + slot) = *(const s16x8*)(xbf + (((size_t)(r0 + tid) * TENC + t) << 3));
      } else {
        s16x8 yv = z;
        ((unsigned short*)&yv)[0] = ybf[(r0 + tid) * TDEC + t];
        *(s16x8*)(wb + slot) = yv;
      }
    }
    // (P1c) encoder -> decoder weight/bias swap (register-only)
    if (s == 256) {
      load_weights(wfa, wfb, w, u0, l15, khi, dWh0, dWx0, 1, dWx1, dWh1);
#pragma unroll
      for (int jj = 0; jj < 2; ++jj) {
        int u = u0 + uslot * 2 + jj;
#pragma unroll
        for (int n = 0; n < 4; ++n) {
          b0s[jj][n] = dB0a[n * 1024 + u] + dB0b[n * 1024 + u];
          b1s[jj][n] = dB1a[n * 1024 + u] + dB1b[n * 1024 + u];
        }
      }
    }
    WAIT_LGKM();        // w0: window writes ordered before its x-slot reads

    // (P2) L0 MFMA over G (G = h0(s-1), staged last step at P7)
    f32x4 acc[2][4];
#pragma unroll
    for (int m = 0; m < 2; ++m)
#pragma unroll
      for (int n = 0; n < 4; ++n) acc[m][n] = {0.f, 0.f, 0.f, 0.f};
#pragma unroll
    for (int j = 0; j < 8; ++j) {
      int off = (w + 4 * j) << 6;
#pragma unroll
      for (int m = 0; m < 2; ++m) {
        const s16x8 af = *(const s16x8*)(smem + (m * 16 + l15) * GP + ((off + khi * 16) ^ key));
#pragma unroll
        for (int n = 0; n < 4; ++n)
          acc[m][n] = __builtin_amdgcn_mfma_f32_16x16x32_bf16(af, wfa[j][n], acc[m][n], 0, 0, 0);
      }
    }
    if (w == 0) {   // x/y K-slot
#pragma unroll
      for (int m = 0; m < 2; ++m) {
        const s16x8 af = *(const s16x8*)(smem + (m * 16 + l15) * GP + ((2048 + khi * 16) ^ key));
#pragma unroll
        for (int n = 0; n < 4; ++n)
          acc[m][n] = __builtin_amdgcn_mfma_f32_16x16x32_bf16(af, wfa[8][n], acc[m][n], 0, 0, 0);
      }
    }

    // (P4) exchange L0 partials -> exG (overlays G rows 0-15)
    WAIT_LGKM();
    BARRIER();            // all waves done reading G
    {
      float* exw = (float*)smem;
#pragma unroll
      for (int m = 0; m < 2; ++m)
#pragma unroll
        for (int n = 0; n < 4; ++n)
#pragma unroll
          for (int r = 0; r < 4; ++r)
            exw[(w * 32 + m * 16 + khi * 4 + r) * EXP + n * 16 + l15] = acc[m][n][r];
    }
    WAIT_LGKM();
    BARRIER();
    WAIT_VM();            // drain H-glds here (shadow = P1b + P2 + P4: ~1.3us)

    // (P5) elementwise L0 + coalesced coherent h0 store
    {
      const float* exw = (const float*)smem;
      unsigned short* hb = h0buf + (((size_t)(par ^ 1) * BATCH + r0 + erow) << 10);
      float hv[2];
#pragma unroll
      for (int jj = 0; jj < 2; ++jj) {
        int u = uslot * 2 + jj;
        float g[4];
#pragma unroll
        for (int n = 0; n < 4; ++n) {
          int c = n * 16 + u;
          g[n] = exw[erow * EXP + c] + exw[(32 + erow) * EXP + c]
               + exw[(64 + erow) * EXP + c] + exw[(96 + erow) * EXP + c] + b0s[jj][n];
        }
        float cv = jj ? c0b : c0a;
        float cn = sigm(g[1]) * cv + sigm(g[0]) * tanh_f(g[2]);
        if (jj) c0b = cn; else c0a = cn;
        hv[jj] = sigm(g[3]) * tanh_f(cn);
      }
      int uswz = (u0 + uslot * 2) ^ ((erow & 7) << 3);
      unsigned pk = (unsigned)f2bf(hv[0]) | ((unsigned)f2bf(hv[1]) << 16);
      stcoh((unsigned*)(hb + uswz), pk);
    }
    WAIT_VM();            // h0 store acked (only the store outstanding)
    BARRIER();
    if (tid == 0) atomicAdd(my1, 1u);

    // (P7) bar1 poll immediately (posted just above; wait = skew+RT), then G-DMA issue
    if (w == 3) pollcnt4(cnt1, 16u * (unsigned)(s + 1), lane);
    BARRIER();
#pragma unroll
    for (int rr = 0; rr < 8; ++rr) {
      int row = w * 8 + rr;
      const char* src = (const char*)(h0buf + (((size_t)(par ^ 1) * BATCH + r0 + row) << 10));
      char* dst = smem + row * GP;
      glds16c(src + lane * 16, dst);
      glds16c(src + 1024 + lane * 16, dst + 1024);
    }
    // (P8) FULL upper MFMA on H (h1 x Whh1), j=8..15 — the G-DMA shadow (~0.6us)
    f32x4 bcc[2][4];
#pragma unroll
    for (int m = 0; m < 2; ++m)
#pragma unroll
      for (int n = 0; n < 4; ++n) bcc[m][n] = {0.f, 0.f, 0.f, 0.f};
#pragma unroll
    for (int j = 8; j < 16; ++j) {
      int off = (w + 4 * (j - 8)) << 6;
#pragma unroll
      for (int m = 0; m < 2; ++m) {
        const s16x8 af = *(const s16x8*)(smem + HOFF + (m * 16 + l15) * HP + ((off + khi * 16) ^ key));
#pragma unroll
        for (int n = 0; n < 4; ++n)
          bcc[m][n] = __builtin_amdgcn_mfma_f32_16x16x32_bf16(af, wfb[j][n], bcc[m][n], 0, 0, 0);
      }
    }
    WAIT_VM();            // G rows landed (only G-glds outstanding)
    BARRIER();
    // (P9) lower MFMA on G (h0(s) x Wih1)
#pragma unroll
    for (int j = 0; j < 8; ++j) {
      int off = (w + 4 * j) << 6;
#pragma unroll
      for (int m = 0; m < 2; ++m) {
        const s16x8 af = *(const s16x8*)(smem + (m * 16 + l15) * GP + ((off + khi * 16) ^ key));
#pragma unroll
        for (int n = 0; n < 4; ++n)
          bcc[m][n] = __builtin_amdgcn_mfma_f32_16x16x32_bf16(af, wfb[j][n], bcc[m][n], 0, 0, 0);
      }
    }
    WAIT_LGKM();
    BARRIER();
    // (P10) exchange L1 partials -> exH (overlays H rows 0-16; H reads done at P8-end)
    {
      float* exw = (float*)(smem + HOFF);
#pragma unroll
      for (int m = 0; m < 2; ++m)
#pragma unroll
        for (int n = 0; n < 4; ++n)
#pragma unroll
          for (int r = 0; r < 4; ++r)
            exw[(w * 32 + m * 16 + khi * 4 + r) * EXP + n * 16 + l15] = bcc[m][n][r];
    }
    WAIT_LGKM();
    BARRIER();
    // (P11) elementwise L1 + coherent h1 store + decoder partial stores (plain)
    {
      const float* exw = (const float*)(smem + HOFF);
      unsigned short* hb = h1buf + (((size_t)(par ^ 1) * BATCH + r0 + erow) << 10);
      float hv[2];
#pragma unroll
      for (int jj = 0; jj < 2; ++jj) {
        int u = uslot * 2 + jj;
        float g[4];
#pragma unroll
        for (int n = 0; n < 4; ++n) {
          int c = n * 16 + u;
          g[n] = exw[erow * EXP + c] + exw[(32 + erow) * EXP + c]
               + exw[(64 + erow) * EXP + c] + exw[(96 + erow) * EXP + c] + b1s[jj][n];
        }
        float cv = jj ? c1b : c1a;
        float cn = sigm(g[1]) * cv + sigm(g[0]) * tanh_f(g[2]);
        if (jj) c1b = cn; else c1a = cn;
        hv[jj] = sigm(g[3]) * tanh_f(cn);
      }
      int uswz = (u0 + uslot * 2) ^ ((erow & 7) << 3);
      unsigned pk = (unsigned)f2bf(hv[0]) | ((unsigned)f2bf(hv[1]) << 16);
      stcoh((unsigned*)(hb + uswz), pk);
      if (!enc) {     // per-WG mu/sig partials: shuffle-reduce + plain store, no atomics
        float sm = hv[0] * wm0 + hv[1] * wm1;
        float sg = hv[0] * wg0 + hv[1] * wg1;
#pragma unroll
        for (int o = 1; o < 8; o <<= 1) { sm += __shfl_xor(sm, o); sg += __shfl_xor(sg, o); }
        if ((tid & 7) == 0) {
          size_t idx = (((size_t)t * 4 + btile) * 64 + utile) * 32 + erow;
          pmu[idx] = sm;
          psg[idx] = sg;
        }
      }
    }
    WAIT_VM();
    BARRIER();
    if (tid == 0) atomicAdd(my2, 1u);
  }
}

// ---------------- epilogue: reduce partials + bias + softplus ----------------
__global__ void finalize_k(const float* __restrict__ pmu, const float* __restrict__ psg,
                           const float* __restrict__ bmu, const float* __restrict__ bsig,
                           float* __restrict__ out) {
  int i = blockIdx.x * 256 + threadIdx.x;
  if (i >= 16384) return;
  int b = i & 127, t = i >> 7;
  int bt = b >> 5, er = b & 31;
  const float* pm = pmu + (((size_t)t * 4 + bt) * 64) * 32 + er;
  const float* ps = psg + (((size_t)t * 4 + bt) * 64) * 32 + er;
  float m = 0.f, sv = 0.f;
#pragma unroll 8
  for (int u = 0; u < 64; ++u) { m += pm[u * 32]; sv += ps[u * 32]; }
  m += bmu[0];
  sv += bsig[0];
  float sp = sv > 20.f ? sv : log1pf(__expf(sv));
  out[16384 + b * 128 + t] = m;     // mu  [b][t][1]
  out[32768 + b * 128 + t] = sp;    // sigma
}

extern "C" void kernel_launch(void* const* d_in, const int* in_sizes, int n_in,
                              void* d_out, int out_size, void* d_ws, size_t ws_size,
                              hipStream_t stream) {
  const float* x    = (const float*)d_in[0];
  const float* y    = (const float*)d_in[1];
  const float* eWx0 = (const float*)d_in[2];
  const float* eWh0 = (const float*)d_in[3];
  const float* eB0a = (const float*)d_in[4];
  const float* eB0b = (const float*)d_in[5];
  const float* eWx1 = (const float*)d_in[6];
  const float* eWh1 = (const float*)d_in[7];
  const float* eB1a = (const float*)d_in[8];
  const float* eB1b = (const float*)d_in[9];
  const float* dWx0 = (const float*)d_in[10];
  const float* dWh0 = (const float*)d_in[11];
  const float* dB0a = (const float*)d_in[12];
  const float* dB0b = (const float*)d_in[13];
  const float* dWx1 = (const float*)d_in[14];
  const float* dWh1 = (const float*)d_in[15];
  const float* dB1a = (const float*)d_in[16];
  const float* dB1b = (const float*)d_in[17];
  const float* Wmu  = (const float*)d_in[18];
  const float* bmu  = (const float*)d_in[19];
  const float* Wsig = (const float*)d_in[20];
  const float* bsig = (const float*)d_in[21];

  char* ws = (char*)d_ws;
  unsigned short* xbf = (unsigned short*)(ws + OFF_XBF);
  unsigned short* ybf = (unsigned short*)(ws + OFF_YBF);
  unsigned short* h0b = (unsigned short*)(ws + OFF_H0);
  unsigned short* h1b = (unsigned short*)(ws + OFF_H1);
  float* pmu = (float*)(ws + OFF_PMU);
  float* psg = (float*)(ws + OFF_PSG);
  unsigned* bars = (unsigned*)(ws + OFF_BAR);

  hipMemsetAsync(ws + OFF_H0, 0, WS_END - OFF_H0, stream);
  hipMemsetAsync(d_out, 0, (size_t)16384 * 4, stream);

  cvt_inputs<<<1024, 256, 0, stream>>>(x, y, xbf, ybf);
  lstm_main<<<256, 256, 0, stream>>>(eWx0, eWh0, eB0a, eB0b, eWx1, eWh1, eB1a, eB1b,
                                     dWx0, dWh0, dB0a, dB0b, dWx1, dWh1, dB1a, dB1b,
                                     Wmu, Wsig, xbf, ybf, h0b, h1b, pmu, psg, bars);
  finalize_k<<<64, 256, 0, stream>>>(pmu, psg, bmu, bsig, (float*)d_out);
}

// Round 13
// 3223.399 us; speedup vs baseline: 1.5227x; 1.5227x over previous
//
#include <hip/hip_runtime.h>
#include <stdint.h>

// ---------------- problem constants ----------------
#define BATCH  128
#define TENC   256
#define TDEC   128
#define NSTEPS 384      // 256 encoder + 128 decoder timesteps
#define GP     2176     // G tile pitch bytes (h0 cols + 128B x/y XOR window)
#define HP     2048     // H tile pitch bytes (h1 cols)
#define HOFF   69632    // G = 32*2176 bytes, H starts here
#define SMEMSZ 135168   // 69632 + 32*2048
#define EXP    65       // exchange pitch in f32 words

typedef __attribute__((ext_vector_type(8))) short s16x8;
typedef __attribute__((ext_vector_type(4))) float f32x4;

// ---------------- workspace layout (bytes) ----------------
#define OFF_XBF 0u         // x bf16 [128][256][8]       512 KB
#define OFF_YBF 524288u    // y bf16 [128][128]           32 KB
#define OFF_H0  557056u    // h0 [2 par][128][1024] bf16, u-swizzled  512 KB
#define OFF_H1  1081344u   // h1 same                                 512 KB
#define OFF_BAR 1736704u   // [4 btile] x 2KB: cnt1 sub[4]@+i*256B, cnt2 sub[4]@+1KB+i*256B
#define WS_END  1744896u
#define OFF_PMU 2097152u   // mu partials  [128 t][4 bt][64 ut][32 er] f32 = 4 MB
#define OFF_PSG 6291456u   // sig partials  4 MB

__device__ __forceinline__ unsigned short f2bf(float f) {   // f32 -> bf16 RNE
  unsigned u = __float_as_uint(f);
  u = u + 0x7fffu + ((u >> 16) & 1u);
  return (unsigned short)(u >> 16);
}
__device__ __forceinline__ float sigm(float x) { return 1.f / (1.f + __expf(-x)); }
__device__ __forceinline__ float tanh_f(float x) {
  float a = fabsf(x);
  float e = __expf(-2.f * a);
  float t = (1.f - e) / (1.f + e);
  return x < 0.f ? -t : t;
}

// async global->LDS 16B/lane, COHERENT (sc0|sc1 = CPol 17): bypass stale L1/L2
__device__ __forceinline__ void glds16c(const void* g, void* l) {
  __builtin_amdgcn_global_load_lds((const __attribute__((address_space(1))) void*)g,
                                   (__attribute__((address_space(3))) void*)l, 16, 0, 17);
}
__device__ __forceinline__ unsigned ldcoh(const unsigned* p) {
  unsigned v;
  asm volatile("global_load_dword %0, %1, off sc0 sc1\n\ts_waitcnt vmcnt(0)"
               : "=v"(v) : "v"(p) : "memory");
  return v;
}
__device__ __forceinline__ void stcoh(unsigned* p, unsigned v) {
  asm volatile("global_store_dword %0, %1, off sc0 sc1" :: "v"(p), "v"(v) : "memory");
}
// 4-line split-counter poll: lanes read line (lane&3); 256B/iter footprint; one wave
__device__ __forceinline__ void pollcnt4(const unsigned* base, unsigned target, int lane) {
  const unsigned* p = base + (lane & 3) * 64;
  for (;;) {
    unsigned v = ldcoh(p);
    if (__all((int)v >= (int)target)) break;
    __builtin_amdgcn_s_sleep(1);
  }
}

#define BARRIER() do { __builtin_amdgcn_s_barrier(); asm volatile("" ::: "memory"); } while (0)
#define WAIT_LGKM() asm volatile("s_waitcnt lgkmcnt(0)" ::: "memory")
#define WAIT_VM()   asm volatile("s_waitcnt vmcnt(0)" ::: "memory")

// -------- resident-weight loader (bf16 MFMA B-frags, K-split stride-4 over waves) --------
__device__ __forceinline__ void load_weights(
    s16x8 (&wfa)[9][4], s16x8 (&wfb)[16][4],
    int w, int u0, int l15, int khi,
    const float* W0h, const float* W0x, int xk,
    const float* W1x, const float* W1h) {
#pragma unroll
  for (int j = 0; j < 9; ++j) {
    int kst = w + 4 * j;
#pragma unroll
    for (int n = 0; n < 4; ++n) {
      int g = n * 1024 + u0 + l15;
      s16x8 v;
#pragma unroll
      for (int e = 0; e < 8; ++e) ((unsigned short*)&v)[e] = 0;
      if (kst < 32) {
        const float* p = W0h + (size_t)g * 1024 + kst * 32 + khi * 8;
#pragma unroll
        for (int e = 0; e < 8; ++e) ((unsigned short*)&v)[e] = f2bf(p[e]);
      } else if (kst == 32) {
        if (khi == 0) {
#pragma unroll
          for (int e = 0; e < 8; ++e)
            if (e < xk) ((unsigned short*)&v)[e] = f2bf(W0x[(size_t)g * xk + e]);
        }
      }
      wfa[j][n] = v;
    }
  }
#pragma unroll
  for (int j = 0; j < 16; ++j) {
    int kst = w + 4 * j;
#pragma unroll
    for (int n = 0; n < 4; ++n) {
      int g = n * 1024 + u0 + l15;
      const float* p = (kst < 32)
          ? (W1x + (size_t)g * 1024 + kst * 32 + khi * 8)
          : (W1h + (size_t)g * 1024 + (kst - 32) * 32 + khi * 8);
      s16x8 v;
#pragma unroll
      for (int e = 0; e < 8; ++e) ((unsigned short*)&v)[e] = f2bf(p[e]);
      wfb[j][n] = v;
    }
  }
}

// ---------------- input conversion ----------------
__global__ void cvt_inputs(const float* __restrict__ x, const float* __restrict__ y,
                           unsigned short* __restrict__ xbf, unsigned short* __restrict__ ybf) {
  int i = blockIdx.x * 256 + threadIdx.x;
  if (i < 262144) xbf[i] = f2bf(x[i]);
  if (i < 16384) {
    int b = i >> 7, t = i & 127;
    ybf[i] = f2bf(y[b * 129 + t]);
  }
}

// ---------------- main persistent kernel ----------------
__global__ void __launch_bounds__(256, 1) lstm_main(
    const float* __restrict__ eWx0, const float* __restrict__ eWh0,
    const float* __restrict__ eB0a, const float* __restrict__ eB0b,
    const float* __restrict__ eWx1, const float* __restrict__ eWh1,
    const float* __restrict__ eB1a, const float* __restrict__ eB1b,
    const float* __restrict__ dWx0, const float* __restrict__ dWh0,
    const float* __restrict__ dB0a, const float* __restrict__ dB0b,
    const float* __restrict__ dWx1, const float* __restrict__ dWh1,
    const float* __restrict__ dB1a, const float* __restrict__ dB1b,
    const float* __restrict__ Wmu, const float* __restrict__ Wsig,
    const unsigned short* __restrict__ xbf, const unsigned short* __restrict__ ybf,
    unsigned short* h0buf, unsigned short* h1buf,
    float* pmu, float* psg, unsigned* bars) {
  __shared__ char smem[SMEMSZ];

  const int tid = threadIdx.x;
  const int wg = blockIdx.x;
  const int w = tid >> 6;
  const int lane = tid & 63;
  const int l15 = lane & 15;
  const int khi = lane >> 4;
  const int btile = wg & 3;        // sync group
  const int utile = wg >> 2;       // 0..63 -> 16 hidden units
  const int u0 = utile << 4;
  const int r0 = btile << 5;       // 32 batch rows
  const int key = (l15 & 7) << 4;  // XOR bank swizzle

  unsigned* cnt1 = bars + btile * 512;       // 4 sub-lines at +i*64 dwords (256B apart)
  unsigned* cnt2 = cnt1 + 256;               // 4 sub-lines, 1KB away
  unsigned* my1 = cnt1 + (utile & 3) * 64;
  unsigned* my2 = cnt2 + (utile & 3) * 64;

  // elementwise partition: erow = tid>>3 (coalesced stores), uslot = tid&7
  const int erow = tid >> 3;
  const int uslot = tid & 7;

  s16x8 wfa[9][4];
  s16x8 wfb[16][4];
  load_weights(wfa, wfb, w, u0, l15, khi, eWh0, eWx0, 8, eWx1, eWh1);

  float b0s[2][4], b1s[2][4];
#pragma unroll
  for (int jj = 0; jj < 2; ++jj) {
    int u = u0 + uslot * 2 + jj;
#pragma unroll
    for (int n = 0; n < 4; ++n) {
      b0s[jj][n] = eB0a[n * 1024 + u] + eB0b[n * 1024 + u];
      b1s[jj][n] = eB1a[n * 1024 + u] + eB1b[n * 1024 + u];
    }
  }
  const float wm0 = Wmu[u0 + uslot * 2], wm1 = Wmu[u0 + uslot * 2 + 1];
  const float wg0 = Wsig[u0 + uslot * 2], wg1 = Wsig[u0 + uslot * 2 + 1];

  float c0a = 0.f, c0b = 0.f, c1a = 0.f, c1b = 0.f;

  // pre-loop: zero G + H tiles, then write x(t=0) window
  {
    s16x8 z;
#pragma unroll
    for (int e = 0; e < 8; ++e) ((unsigned short*)&z)[e] = 0;
    for (int o = tid * 16; o < SMEMSZ; o += 4096) *(s16x8*)(smem + o) = z;
  }
  __syncthreads();
  if (tid < 32) {
    char* wb = smem + tid * GP + 2048 + ((tid & 7) << 4);
    *(s16x8*)wb = *(const s16x8*)(xbf + (((size_t)(r0 + tid) * TENC) << 3));
  }
  __syncthreads();

  for (int s = 0; s < NSTEPS; ++s) {
    const int enc = (s < 256) ? 1 : 0;
    const int t = enc ? s : (s - 256);
    const int par = s & 1;

    // (P1c) encoder -> decoder weight/bias swap (register-only; no sync needed)
    if (s == 256) {
      load_weights(wfa, wfb, w, u0, l15, khi, dWh0, dWx0, 1, dWx1, dWh1);
#pragma unroll
      for (int jj = 0; jj < 2; ++jj) {
        int u = u0 + uslot * 2 + jj;
#pragma unroll
        for (int n = 0; n < 4; ++n) {
          b0s[jj][n] = dB0a[n * 1024 + u] + dB0b[n * 1024 + u];
          b1s[jj][n] = dB1a[n * 1024 + u] + dB1b[n * 1024 + u];
        }
      }
    }

    // (P2) L0 MFMA over G (G = h0(s-1) staged last step at P7; window written at P6-prev)
    f32x4 acc[2][4];
#pragma unroll
    for (int m = 0; m < 2; ++m)
#pragma unroll
      for (int n = 0; n < 4; ++n) acc[m][n] = {0.f, 0.f, 0.f, 0.f};
#pragma unroll
    for (int j = 0; j < 8; ++j) {
      int off = (w + 4 * j) << 6;
#pragma unroll
      for (int m = 0; m < 2; ++m) {
        const s16x8 af = *(const s16x8*)(smem + (m * 16 + l15) * GP + ((off + khi * 16) ^ key));
#pragma unroll
        for (int n = 0; n < 4; ++n)
          acc[m][n] = __builtin_amdgcn_mfma_f32_16x16x32_bf16(af, wfa[j][n], acc[m][n], 0, 0, 0);
      }
    }
    if (w == 0) {   // x/y K-slot
#pragma unroll
      for (int m = 0; m < 2; ++m) {
        const s16x8 af = *(const s16x8*)(smem + (m * 16 + l15) * GP + ((2048 + khi * 16) ^ key));
#pragma unroll
        for (int n = 0; n < 4; ++n)
          acc[m][n] = __builtin_amdgcn_mfma_f32_16x16x32_bf16(af, wfa[8][n], acc[m][n], 0, 0, 0);
      }
    }

    // (P3) bar2(s-1): wave-3 poll (skew absorbed by P2) + barrier release, H-DMA issue
    if (w == 3) pollcnt4(cnt2, 16u * (unsigned)s, lane);
    BARRIER();
#pragma unroll
    for (int rr = 0; rr < 8; ++rr) {
      int row = w * 8 + rr;
      const char* src = (const char*)(h1buf + (((size_t)par * BATCH + r0 + row) << 10));
      char* dst = smem + HOFF + row * HP;
      glds16c(src + lane * 16, dst);
      glds16c(src + 1024 + lane * 16, dst + 1024);
    }

    // (P4) exchange L0 partials -> exG (overlays G rows 0-15)
    WAIT_LGKM();
    BARRIER();            // all waves done reading G
    {
      float* exw = (float*)smem;
#pragma unroll
      for (int m = 0; m < 2; ++m)
#pragma unroll
        for (int n = 0; n < 4; ++n)
#pragma unroll
          for (int r = 0; r < 4; ++r)
            exw[(w * 32 + m * 16 + khi * 4 + r) * EXP + n * 16 + l15] = acc[m][n][r];
    }
    WAIT_LGKM();
    BARRIER();
    WAIT_VM();            // drain H-glds EARLY (shadowed by P2+P4) so post-drain is store-only

    // (P5) elementwise L0 + coalesced coherent h0 store
    {
      const float* exw = (const float*)smem;
      unsigned short* hb = h0buf + (((size_t)(par ^ 1) * BATCH + r0 + erow) << 10);
      float hv[2];
#pragma unroll
      for (int jj = 0; jj < 2; ++jj) {
        int u = uslot * 2 + jj;
        float g[4];
#pragma unroll
        for (int n = 0; n < 4; ++n) {
          int c = n * 16 + u;
          g[n] = exw[erow * EXP + c] + exw[(32 + erow) * EXP + c]
               + exw[(64 + erow) * EXP + c] + exw[(96 + erow) * EXP + c] + b0s[jj][n];
        }
        float cv = jj ? c0b : c0a;
        float cn = sigm(g[1]) * cv + sigm(g[0]) * tanh_f(g[2]);
        if (jj) c0b = cn; else c0a = cn;
        hv[jj] = sigm(g[3]) * tanh_f(cn);
      }
      int uswz = (u0 + uslot * 2) ^ ((erow & 7) << 3);
      unsigned pk = (unsigned)f2bf(hv[0]) | ((unsigned)f2bf(hv[1]) << 16);
      stcoh((unsigned*)(hb + uswz), pk);
    }
    WAIT_VM();            // h0 store acked (only the store outstanding)
    BARRIER();
    if (tid == 0) atomicAdd(my1, 1u);

    // (P6) F0-poll shadow: x/y window write for step s+1 (w0-only, wave-local)
    //      + upper MFMA part A on H (h1 x Whh1), j=8..11
    if (s < NSTEPS - 1 && tid < 32) {
      char* wb = smem + tid * GP + 2048;
      s16x8 z;
#pragma unroll
      for (int e = 0; e < 8; ++e) ((unsigned short*)&z)[e] = 0;
#pragma unroll
      for (int q = 0; q < 8; ++q) *(s16x8*)(wb + q * 16) = z;   // clear exG residue
      int slot = (tid & 7) << 4;
      int s1 = s + 1;
      if (s1 < 256) {
        *(s16x8*)(wb + slot) = *(const s16x8*)(xbf + (((size_t)(r0 + tid) * TENC + s1) << 3));
      } else {
        s16x8 yv = z;
        ((unsigned short*)&yv)[0] = ybf[(r0 + tid) * TDEC + (s1 - 256)];
        *(s16x8*)(wb + slot) = yv;
      }
    }
    f32x4 bcc[2][4];
#pragma unroll
    for (int m = 0; m < 2; ++m)
#pragma unroll
      for (int n = 0; n < 4; ++n) bcc[m][n] = {0.f, 0.f, 0.f, 0.f};
#pragma unroll
    for (int j = 8; j < 12; ++j) {
      int off = (w + 4 * (j - 8)) << 6;
#pragma unroll
      for (int m = 0; m < 2; ++m) {
        const s16x8 af = *(const s16x8*)(smem + HOFF + (m * 16 + l15) * HP + ((off + khi * 16) ^ key));
#pragma unroll
        for (int n = 0; n < 4; ++n)
          bcc[m][n] = __builtin_amdgcn_mfma_f32_16x16x32_bf16(af, wfb[j][n], bcc[m][n], 0, 0, 0);
      }
    }
    // (P7) bar1 poll (posted just above; shadow = P6), then G-DMA issue
    if (w == 3) pollcnt4(cnt1, 16u * (unsigned)(s + 1), lane);
    BARRIER();
#pragma unroll
    for (int rr = 0; rr < 8; ++rr) {
      int row = w * 8 + rr;
      const char* src = (const char*)(h0buf + (((size_t)(par ^ 1) * BATCH + r0 + row) << 10));
      char* dst = smem + row * GP;
      glds16c(src + lane * 16, dst);
      glds16c(src + 1024 + lane * 16, dst + 1024);
    }
    // (P8) upper MFMA part B, j=12..15 — hides G-stage L3 latency
#pragma unroll
    for (int j = 12; j < 16; ++j) {
      int off = (w + 4 * (j - 8)) << 6;
#pragma unroll
      for (int m = 0; m < 2; ++m) {
        const s16x8 af = *(const s16x8*)(smem + HOFF + (m * 16 + l15) * HP + ((off + khi * 16) ^ key));
#pragma unroll
        for (int n = 0; n < 4; ++n)
          bcc[m][n] = __builtin_amdgcn_mfma_f32_16x16x32_bf16(af, wfb[j][n], bcc[m][n], 0, 0, 0);
      }
    }
    WAIT_VM();            // G rows landed (only G-glds outstanding)
    BARRIER();
    // (P9) lower MFMA on G (h0(s) x Wih1)
#pragma unroll
    for (int j = 0; j < 8; ++j) {
      int off = (w + 4 * j) << 6;
#pragma unroll
      for (int m = 0; m < 2; ++m) {
        const s16x8 af = *(const s16x8*)(smem + (m * 16 + l15) * GP + ((off + khi * 16) ^ key));
#pragma unroll
        for (int n = 0; n < 4; ++n)
          bcc[m][n] = __builtin_amdgcn_mfma_f32_16x16x32_bf16(af, wfb[j][n], bcc[m][n], 0, 0, 0);
      }
    }
    WAIT_LGKM();
    BARRIER();
    // (P10) exchange L1 partials -> exH (overlays H rows 0-16)
    {
      float* exw = (float*)(smem + HOFF);
#pragma unroll
      for (int m = 0; m < 2; ++m)
#pragma unroll
        for (int n = 0; n < 4; ++n)
#pragma unroll
          for (int r = 0; r < 4; ++r)
            exw[(w * 32 + m * 16 + khi * 4 + r) * EXP + n * 16 + l15] = bcc[m][n][r];
    }
    WAIT_LGKM();
    BARRIER();
    // (P11) elementwise L1 + coherent h1 store; partial STORES deferred past the post
    float sm = 0.f, sg = 0.f;
    {
      const float* exw = (const float*)(smem + HOFF);
      unsigned short* hb = h1buf + (((size_t)(par ^ 1) * BATCH + r0 + erow) << 10);
      float hv[2];
#pragma unroll
      for (int jj = 0; jj < 2; ++jj) {
        int u = uslot * 2 + jj;
        float g[4];
#pragma unroll
        for (int n = 0; n < 4; ++n) {
          int c = n * 16 + u;
          g[n] = exw[erow * EXP + c] + exw[(32 + erow) * EXP + c]
               + exw[(64 + erow) * EXP + c] + exw[(96 + erow) * EXP + c] + b1s[jj][n];
        }
        float cv = jj ? c1b : c1a;
        float cn = sigm(g[1]) * cv + sigm(g[0]) * tanh_f(g[2]);
        if (jj) c1b = cn; else c1a = cn;
        hv[jj] = sigm(g[3]) * tanh_f(cn);
      }
      int uswz = (u0 + uslot * 2) ^ ((erow & 7) << 3);
      unsigned pk = (unsigned)f2bf(hv[0]) | ((unsigned)f2bf(hv[1]) << 16);
      stcoh((unsigned*)(hb + uswz), pk);
      if (!enc) {     // shuffle-reduce now (VALU), store later (off the F1 drain)
        sm = hv[0] * wm0 + hv[1] * wm1;
        sg = hv[0] * wg0 + hv[1] * wg1;
#pragma unroll
        for (int o = 1; o < 8; o <<= 1) { sm += __shfl_xor(sm, o); sg += __shfl_xor(sg, o); }
      }
    }
    WAIT_VM();            // h1 store acked
    BARRIER();
    if (tid == 0) atomicAdd(my2, 1u);
    if (!enc && (tid & 7) == 0) {   // fire-and-forget; drained by next P4 WAIT_VM / loop-end
      size_t idx = (((size_t)t * 4 + btile) * 64 + utile) * 32 + erow;
      pmu[idx] = sm;
      psg[idx] = sg;
    }
  }
  WAIT_VM();   // flush the final step's partial stores before wave exit
}

// ---------------- epilogue: reduce partials + bias + softplus ----------------
__global__ void finalize_k(const float* __restrict__ pmu, const float* __restrict__ psg,
                           const float* __restrict__ bmu, const float* __restrict__ bsig,
                           float* __restrict__ out) {
  int i = blockIdx.x * 256 + threadIdx.x;
  if (i >= 16384) return;
  int b = i & 127, t = i >> 7;
  int bt = b >> 5, er = b & 31;
  const float* pm = pmu + (((size_t)t * 4 + bt) * 64) * 32 + er;
  const float* ps = psg + (((size_t)t * 4 + bt) * 64) * 32 + er;
  float m = 0.f, sv = 0.f;
#pragma unroll 8
  for (int u = 0; u < 64; ++u) { m += pm[u * 32]; sv += ps[u * 32]; }
  m += bmu[0];
  sv += bsig[0];
  float sp = sv > 20.f ? sv : log1pf(__expf(sv));
  out[16384 + b * 128 + t] = m;     // mu  [b][t][1]
  out[32768 + b * 128 + t] = sp;    // sigma
}

extern "C" void kernel_launch(void* const* d_in, const int* in_sizes, int n_in,
                              void* d_out, int out_size, void* d_ws, size_t ws_size,
                              hipStream_t stream) {
  const float* x    = (const float*)d_in[0];
  const float* y    = (const float*)d_in[1];
  const float* eWx0 = (const float*)d_in[2];
  const float* eWh0 = (const float*)d_in[3];
  const float* eB0a = (const float*)d_in[4];
  const float* eB0b = (const float*)d_in[5];
  const float* eWx1 = (const float*)d_in[6];
  const float* eWh1 = (const float*)d_in[7];
  const float* eB1a = (const float*)d_in[8];
  const float* eB1b = (const float*)d_in[9];
  const float* dWx0 = (const float*)d_in[10];
  const float* dWh0 = (const float*)d_in[11];
  const float* dB0a = (const float*)d_in[12];
  const float* dB0b = (const float*)d_in[13];
  const float* dWx1 = (const float*)d_in[14];
  const float* dWh1 = (const float*)d_in[15];
  const float* dB1a = (const float*)d_in[16];
  const float* dB1b = (const float*)d_in[17];
  const float* Wmu  = (const float*)d_in[18];
  const float* bmu  = (const float*)d_in[19];
  const float* Wsig = (const float*)d_in[20];
  const float* bsig = (const float*)d_in[21];

  char* ws = (char*)d_ws;
  unsigned short* xbf = (unsigned short*)(ws + OFF_XBF);
  unsigned short* ybf = (unsigned short*)(ws + OFF_YBF);
  unsigned short* h0b = (unsigned short*)(ws + OFF_H0);
  unsigned short* h1b = (unsigned short*)(ws + OFF_H1);
  float* pmu = (float*)(ws + OFF_PMU);
  float* psg = (float*)(ws + OFF_PSG);
  unsigned* bars = (unsigned*)(ws + OFF_BAR);

  hipMemsetAsync(ws + OFF_H0, 0, WS_END - OFF_H0, stream);
  hipMemsetAsync(d_out, 0, (size_t)16384 * 4, stream);

  cvt_inputs<<<1024, 256, 0, stream>>>(x, y, xbf, ybf);
  lstm_main<<<256, 256, 0, stream>>>(eWx0, eWh0, eB0a, eB0b, eWx1, eWh1, eB1a, eB1b,
                                     dWx0, dWh0, dB0a, dB0b, dWx1, dWh1, dB1a, dB1b,
                                     Wmu, Wsig, xbf, ybf, h0b, h1b, pmu, psg, bars);
  finalize_k<<<64, 256, 0, stream>>>(pmu, psg, bmu, bsig, (float*)d_out);
}